// Round 7
// baseline (384.060 us; speedup 1.0000x reference)
//
#include <hip/hip_runtime.h>
#include <hip/hip_bf16.h>

// kNNFit: out[b] = beta * (mean_m F(1 - WHD[m,b]/||W||_1) * Y[m] + alpha)
// WHD[m,b] = s1[b] + sum_d X2[d,m] * (+-W[d]),  sign = (1 - 2*X1[d,b])
// GEMM C[M,64] = X2^T @ (+-W) via mfma_f32_32x32x16_bf16.
// Main: 512-thread blocks (1/CU), MWG=512, int4 X2 loads with 3-deep
// register-slot prefetch (partial vmcnt waits, never drained), wave-private
// LDS transpose (double-buffered, NO __syncthreads in K-loop) -> MFMA.

#define DD 512
#define MM 131072
#define BQ 64
#define MWG 512
#define NWG (MM / MWG)      // 256 blocks (1 per CU); wave owns 64 m's
#define NWAVES (NWG * 8)    // 2048
#define WS_BFRAG 0          // 64 KB: short8[(s*2+t)*64 + lane]
#define WS_META  65536      // float[65]: s1[64], inv_norm
#define WS_PART  131072     // float[64][NWAVES]

typedef __attribute__((ext_vector_type(8))) short short8;        // 8 bf16
typedef __attribute__((ext_vector_type(16))) float floatx16;     // 16 fp32 acc
typedef __attribute__((ext_vector_type(4))) unsigned int uintx4;
typedef __attribute__((ext_vector_type(4))) int intx4;

__global__ __launch_bounds__(256) void knn_setup(
    const int* __restrict__ X1, const float* __restrict__ W,
    void* __restrict__ ws) {
  short8* bm = (short8*)((char*)ws + WS_BFRAG);
  float* meta = (float*)((char*)ws + WS_META);
  const int tid = threadIdx.x;
  const int bid = blockIdx.x;
  if (bid < 16) {
    // B fragments: bm[(s*2+t)*64 + lane] holds B[k=s*16+half*8+j][b=t*32+col]
    const int e = bid * 256 + tid;
    const int lane = e & 63, t = (e >> 6) & 1, s = e >> 7;
    const int half = lane >> 5, col = lane & 31;
    const int b = t * 32 + col;
    short8 f;
#pragma unroll
    for (int j = 0; j < 8; ++j) {
      const int d = s * 16 + half * 8 + j;
      unsigned short hb = __builtin_bit_cast(unsigned short, __float2bfloat16(W[d]));
      if (X1[d * BQ + b]) hb ^= 0x8000u;
      f[j] = (short)hb;
    }
    bm[e] = f;
  } else {
    __shared__ float s1p[4][64];
    const int chunk = tid >> 6, b = tid & 63;
    float s = 0.f;
    for (int d = chunk * 128; d < chunk * 128 + 128; ++d)
      s += W[d] * (float)X1[d * BQ + b];
    s1p[chunk][b] = s;
    __syncthreads();
    if (tid < 64) {
      meta[tid] = s1p[0][tid] + s1p[1][tid] + s1p[2][tid] + s1p[3][tid];
      float nw = 0.f;
#pragma unroll
      for (int j = 0; j < 8; ++j) nw += fabsf(W[tid * 8 + j]);
      nw += __shfl_xor(nw, 32);
      nw += __shfl_xor(nw, 16);
      nw += __shfl_xor(nw, 8);
      nw += __shfl_xor(nw, 4);
      nw += __shfl_xor(nw, 2);
      nw += __shfl_xor(nw, 1);
      if (tid == 0) meta[64] = 1.0f / (nw + 1e-6f);
    }
  }
}

__global__ __launch_bounds__(512, 1) void knn_main(
    const int* __restrict__ X2, const float* __restrict__ Y,
    const float* __restrict__ kp, const float* __restrict__ jp,
    const void* __restrict__ ws_ro, float* __restrict__ partials) {
  const short8* bm = (const short8*)((const char*)ws_ro + WS_BFRAG);
  const float* meta = (const float*)((const char*)ws_ro + WS_META);

  // wave-private double-buffered transpose tile: [64 m][pitch 10 dwords]
  __shared__ __align__(16) unsigned int lds[8][2][640];

  const int tid = threadIdx.x;
  const int wv = tid >> 6, l = tid & 63;
  const int half = l >> 5, col = l & 31;
  const int m0 = blockIdx.x * MWG + wv * 64;
  unsigned int (*buf)[640] = lds[wv];

  const int r = l >> 3;           // row-pair index 0..7 (d = s*16 + 2r, 2r+1)
  const int mo = (l & 7) * 4;     // 4 consecutive m's per lane (within 32-m sub-tile)
  const int wb0 = mo * 10 + r;              // LDS write base, m-sub-tile 0
  const int wb1 = (mo + 32) * 10 + r;       // m-sub-tile 1
  const int rb0 = col * 10 + half * 4;      // LDS read base, sub-tile 0
  const int rb1 = (col + 32) * 10 + half * 4;

  floatx16 a00, a01, a10, a11;
#pragma unroll
  for (int q = 0; q < 16; ++q) { a00[q] = 0.f; a01[q] = 0.f; a10[q] = 0.f; a11[q] = 0.f; }

  const int* g0 = X2 + (size_t)(2 * r) * MM + m0 + mo;

  // 3-deep register prefetch slots: slot t%3 holds step t's 4 int4 loads
  intx4 sa[3], sb[3], sc[3], sd[3];
#pragma unroll
  for (int t = 0; t < 3; ++t) {
    const int* p = g0 + (size_t)t * 16 * MM;
    sa[t] = *(const intx4*)p;
    sb[t] = *(const intx4*)(p + MM);
    sc[t] = *(const intx4*)(p + 32);
    sd[t] = *(const intx4*)(p + MM + 32);
  }
  // pack step 0 (slot 0) -> buf[0]
#pragma unroll
  for (int i = 0; i < 4; ++i) {
    buf[0][wb0 + 10 * i] = (unsigned int)(sa[0][i] | (sb[0][i] << 16)) * 0x3F80u;
    buf[0][wb1 + 10 * i] = (unsigned int)(sc[0][i] | (sd[0][i] << 16)) * 0x3F80u;
  }
  short8 bf0 = bm[0 * 64 + l];
  short8 bf1 = bm[1 * 64 + l];

#pragma unroll
  for (int s = 0; s < 32; ++s) {
    // A-frags for step s from buf[s&1]
    uintx4 u0, u1;
    {
      uint2 lo = *(const uint2*)&buf[s & 1][rb0];
      uint2 hi = *(const uint2*)&buf[s & 1][rb0 + 2];
      u0[0] = lo.x; u0[1] = lo.y; u0[2] = hi.x; u0[3] = hi.y;
      lo = *(const uint2*)&buf[s & 1][rb1];
      hi = *(const uint2*)&buf[s & 1][rb1 + 2];
      u1[0] = lo.x; u1[1] = lo.y; u1[2] = hi.x; u1[3] = hi.y;
    }
    const short8 af0 = __builtin_bit_cast(short8, u0);
    const short8 af1 = __builtin_bit_cast(short8, u1);
    // issue step s+3 loads FIRST (into slot s%3, freed at iter s-1) so the
    // pack below waits with a partial vmcnt, never draining the queue
    if (s + 3 <= 31) {
      const int t = (s + 3) % 3;
      const int* p = g0 + (size_t)(s + 3) * 16 * MM;
      sa[t] = *(const intx4*)p;
      sb[t] = *(const intx4*)(p + MM);
      sc[t] = *(const intx4*)(p + 32);
      sd[t] = *(const intx4*)(p + MM + 32);
    }
    short8 nbf0 = bf0, nbf1 = bf1;
    if (s < 31) {  // pack step s+1 (slot (s+1)%3) -> other LDS buffer (wave-local)
      const int t = (s + 1) % 3;
#pragma unroll
      for (int i = 0; i < 4; ++i) {
        buf[(s + 1) & 1][wb0 + 10 * i] = (unsigned int)(sa[t][i] | (sb[t][i] << 16)) * 0x3F80u;
        buf[(s + 1) & 1][wb1 + 10 * i] = (unsigned int)(sc[t][i] | (sd[t][i] << 16)) * 0x3F80u;
      }
      nbf0 = bm[((s + 1) * 2 + 0) * 64 + l];
      nbf1 = bm[((s + 1) * 2 + 1) * 64 + l];
    }
    a00 = __builtin_amdgcn_mfma_f32_32x32x16_bf16(af0, bf0, a00, 0, 0, 0);
    a01 = __builtin_amdgcn_mfma_f32_32x32x16_bf16(af0, bf1, a01, 0, 0, 0);
    a10 = __builtin_amdgcn_mfma_f32_32x32x16_bf16(af1, bf0, a10, 0, 0, 0);
    a11 = __builtin_amdgcn_mfma_f32_32x32x16_bf16(af1, bf1, a11, 0, 0, 0);
    bf0 = nbf0; bf1 = nbf1;
  }

  // epilogue: squash F, weight by Y, reduce over this wave's 64 m's
  const float inv_norm = meta[64];
  const float kk = kp[0], jj = jp[0];
  const float c1 = 1.0f - kk, c2 = 1.0f + jj;
  const float s1b0 = meta[col];
  const float s1b1 = meta[32 + col];
  float p0 = 0.f, p1 = 0.f;
#pragma unroll
  for (int q = 0; q < 16; ++q) {
    const int ml = (q & 3) + 8 * (q >> 2) + 4 * half;  // verified 32x32 C/D row map
    const float ym0 = Y[m0 + ml];
    const float ym1 = Y[m0 + 32 + ml];
    {
      const float x = 1.0f - (s1b0 + a00[q]) * inv_norm;
      const float inner = x * c1 / (kk * (1.0f - 2.0f * fabsf(x)) + 1.0f);
      const float t2 = 2.0f * inner - 1.0f;
      const float fq = 0.5f + 0.5f * t2 * c2 / (-jj * (1.0f - 2.0f * fabsf(t2)) + 1.0f);
      p0 += fq * ym0;
    }
    {
      const float x = 1.0f - (s1b1 + a01[q]) * inv_norm;
      const float inner = x * c1 / (kk * (1.0f - 2.0f * fabsf(x)) + 1.0f);
      const float t2 = 2.0f * inner - 1.0f;
      const float fq = 0.5f + 0.5f * t2 * c2 / (-jj * (1.0f - 2.0f * fabsf(t2)) + 1.0f);
      p1 += fq * ym0;
    }
    {
      const float x = 1.0f - (s1b0 + a10[q]) * inv_norm;
      const float inner = x * c1 / (kk * (1.0f - 2.0f * fabsf(x)) + 1.0f);
      const float t2 = 2.0f * inner - 1.0f;
      const float fq = 0.5f + 0.5f * t2 * c2 / (-jj * (1.0f - 2.0f * fabsf(t2)) + 1.0f);
      p0 += fq * ym1;
    }
    {
      const float x = 1.0f - (s1b1 + a11[q]) * inv_norm;
      const float inner = x * c1 / (kk * (1.0f - 2.0f * fabsf(x)) + 1.0f);
      const float t2 = 2.0f * inner - 1.0f;
      const float fq = 0.5f + 0.5f * t2 * c2 / (-jj * (1.0f - 2.0f * fabsf(t2)) + 1.0f);
      p1 += fq * ym1;
    }
  }
  p0 += __shfl_xor(p0, 32);  // combine the two lane-halves
  p1 += __shfl_xor(p1, 32);
  const int gw = blockIdx.x * 8 + wv;
  if (l < 32) {
    partials[(size_t)col * NWAVES + gw] = p0;
    partials[(size_t)(32 + col) * NWAVES + gw] = p1;
  }
}

__global__ __launch_bounds__(256) void knn_finalize(
    const float* __restrict__ partials, const float* __restrict__ alphap,
    const float* __restrict__ betap, float* __restrict__ out) {
  __shared__ float red[256];
  const int b = blockIdx.x, t = threadIdx.x;
  float s = 0.f;
#pragma unroll
  for (int i = 0; i < NWAVES / 256; ++i)
    s += partials[(size_t)b * NWAVES + i * 256 + t];
  red[t] = s;
  __syncthreads();
  if (t < 64) {
    float x = red[t] + red[t + 64] + red[t + 128] + red[t + 192];
    x += __shfl_xor(x, 32);
    x += __shfl_xor(x, 16);
    x += __shfl_xor(x, 8);
    x += __shfl_xor(x, 4);
    x += __shfl_xor(x, 2);
    x += __shfl_xor(x, 1);
    if (t == 0) out[b] = betap[0] * (x * (1.0f / (float)MM) + alphap[0]);
  }
}

extern "C" void kernel_launch(void* const* d_in, const int* in_sizes, int n_in,
                              void* d_out, int out_size, void* d_ws, size_t ws_size,
                              hipStream_t stream) {
  const int* X1 = (const int*)d_in[0];     // [512, 64] int32 bits
  const int* X2 = (const int*)d_in[1];     // [512, 131072] int32 bits
  const float* Y = (const float*)d_in[3];  // [131072]
  const float* W = (const float*)d_in[4];  // [512]
  const float* alphap = (const float*)d_in[5];
  const float* betap = (const float*)d_in[6];
  const float* kp = (const float*)d_in[7];
  const float* jp = (const float*)d_in[8];

  float* partials = (float*)((char*)d_ws + WS_PART);

  knn_setup<<<17, 256, 0, stream>>>(X1, W, d_ws);
  knn_main<<<NWG, 512, 0, stream>>>(X2, Y, kp, jp, d_ws, partials);
  knn_finalize<<<BQ, 256, 0, stream>>>(partials, alphap, betap, (float*)d_out);
}

// Round 8
// 361.462 us; speedup vs baseline: 1.0625x; 1.0625x over previous
//
#include <hip/hip_runtime.h>
#include <hip/hip_bf16.h>

// kNNFit: out[b] = beta * (mean_m F(1 - WHD[m,b]/||W||_1) * Y[m] + alpha)
// WHD[m,b] = s1[b] + sum_d X2[d,m] * (+-W[d]),  sign = (1 - 2*X1[d,b])
// GEMM C[M,64] = X2^T @ (+-W) via mfma_f32_32x32x16_bf16.
// Main: 512-thread blocks (1/CU), MWG=512, NONTEMPORAL int4 X2 loads
// (keeps bm/Y resident in L2 while X2 streams) with 3-deep register-slot
// prefetch, wave-private LDS transpose (no __syncthreads in K-loop) -> MFMA.

#define DD 512
#define MM 131072
#define BQ 64
#define MWG 512
#define NWG (MM / MWG)      // 256 blocks (1 per CU); wave owns 64 m's
#define NWAVES (NWG * 8)    // 2048
#define WS_BFRAG 0          // 64 KB: short8[(s*2+t)*64 + lane]
#define WS_META  65536      // float[65]: s1[64], inv_norm
#define WS_PART  131072     // float[64][NWAVES]

typedef __attribute__((ext_vector_type(8))) short short8;        // 8 bf16
typedef __attribute__((ext_vector_type(16))) float floatx16;     // 16 fp32 acc
typedef __attribute__((ext_vector_type(4))) unsigned int uintx4;
typedef __attribute__((ext_vector_type(4))) int intx4;

__global__ __launch_bounds__(256) void knn_setup(
    const int* __restrict__ X1, const float* __restrict__ W,
    void* __restrict__ ws) {
  short8* bm = (short8*)((char*)ws + WS_BFRAG);
  float* meta = (float*)((char*)ws + WS_META);
  const int tid = threadIdx.x;
  const int bid = blockIdx.x;
  if (bid < 16) {
    // B fragments: bm[(s*2+t)*64 + lane] holds B[k=s*16+half*8+j][b=t*32+col]
    const int e = bid * 256 + tid;
    const int lane = e & 63, t = (e >> 6) & 1, s = e >> 7;
    const int half = lane >> 5, col = lane & 31;
    const int b = t * 32 + col;
    short8 f;
#pragma unroll
    for (int j = 0; j < 8; ++j) {
      const int d = s * 16 + half * 8 + j;
      unsigned short hb = __builtin_bit_cast(unsigned short, __float2bfloat16(W[d]));
      if (X1[d * BQ + b]) hb ^= 0x8000u;
      f[j] = (short)hb;
    }
    bm[e] = f;
  } else {
    __shared__ float s1p[4][64];
    const int chunk = tid >> 6, b = tid & 63;
    float s = 0.f;
    for (int d = chunk * 128; d < chunk * 128 + 128; ++d)
      s += W[d] * (float)X1[d * BQ + b];
    s1p[chunk][b] = s;
    __syncthreads();
    if (tid < 64) {
      meta[tid] = s1p[0][tid] + s1p[1][tid] + s1p[2][tid] + s1p[3][tid];
      float nw = 0.f;
#pragma unroll
      for (int j = 0; j < 8; ++j) nw += fabsf(W[tid * 8 + j]);
      nw += __shfl_xor(nw, 32);
      nw += __shfl_xor(nw, 16);
      nw += __shfl_xor(nw, 8);
      nw += __shfl_xor(nw, 4);
      nw += __shfl_xor(nw, 2);
      nw += __shfl_xor(nw, 1);
      if (tid == 0) meta[64] = 1.0f / (nw + 1e-6f);
    }
  }
}

__global__ __launch_bounds__(512, 1) void knn_main(
    const int* __restrict__ X2, const float* __restrict__ Y,
    const float* __restrict__ kp, const float* __restrict__ jp,
    const void* __restrict__ ws_ro, float* __restrict__ partials) {
  const short8* bm = (const short8*)((const char*)ws_ro + WS_BFRAG);
  const float* meta = (const float*)((const char*)ws_ro + WS_META);

  // wave-private double-buffered transpose tile: [64 m][pitch 10 dwords]
  __shared__ __align__(16) unsigned int lds[8][2][640];

  const int tid = threadIdx.x;
  const int wv = tid >> 6, l = tid & 63;
  const int half = l >> 5, col = l & 31;
  const int m0 = blockIdx.x * MWG + wv * 64;
  unsigned int (*buf)[640] = lds[wv];

  const int r = l >> 3;           // row-pair index 0..7 (d = s*16 + 2r, 2r+1)
  const int mo = (l & 7) * 4;     // 4 consecutive m's per lane (within 32-m sub-tile)
  const int wb0 = mo * 10 + r;              // LDS write base, m-sub-tile 0
  const int wb1 = (mo + 32) * 10 + r;       // m-sub-tile 1
  const int rb0 = col * 10 + half * 4;      // LDS read base, sub-tile 0
  const int rb1 = (col + 32) * 10 + half * 4;

  floatx16 a00, a01, a10, a11;
#pragma unroll
  for (int q = 0; q < 16; ++q) { a00[q] = 0.f; a01[q] = 0.f; a10[q] = 0.f; a11[q] = 0.f; }

  const int* g0 = X2 + (size_t)(2 * r) * MM + m0 + mo;

  // 3-deep register prefetch slots: slot t%3 holds step t's 4 int4 loads
  intx4 sa[3], sb[3], sc[3], sd[3];
#pragma unroll
  for (int t = 0; t < 3; ++t) {
    const int* p = g0 + (size_t)t * 16 * MM;
    sa[t] = __builtin_nontemporal_load((const intx4*)p);
    sb[t] = __builtin_nontemporal_load((const intx4*)(p + MM));
    sc[t] = __builtin_nontemporal_load((const intx4*)(p + 32));
    sd[t] = __builtin_nontemporal_load((const intx4*)(p + MM + 32));
  }
  // pack step 0 (slot 0) -> buf[0]
#pragma unroll
  for (int i = 0; i < 4; ++i) {
    buf[0][wb0 + 10 * i] = (unsigned int)(sa[0][i] | (sb[0][i] << 16)) * 0x3F80u;
    buf[0][wb1 + 10 * i] = (unsigned int)(sc[0][i] | (sd[0][i] << 16)) * 0x3F80u;
  }
  short8 bf0 = bm[0 * 64 + l];
  short8 bf1 = bm[1 * 64 + l];

#pragma unroll
  for (int s = 0; s < 32; ++s) {
    // A-frags for step s from buf[s&1]
    uintx4 u0, u1;
    {
      uint2 lo = *(const uint2*)&buf[s & 1][rb0];
      uint2 hi = *(const uint2*)&buf[s & 1][rb0 + 2];
      u0[0] = lo.x; u0[1] = lo.y; u0[2] = hi.x; u0[3] = hi.y;
      lo = *(const uint2*)&buf[s & 1][rb1];
      hi = *(const uint2*)&buf[s & 1][rb1 + 2];
      u1[0] = lo.x; u1[1] = lo.y; u1[2] = hi.x; u1[3] = hi.y;
    }
    const short8 af0 = __builtin_bit_cast(short8, u0);
    const short8 af1 = __builtin_bit_cast(short8, u1);
    // issue step s+3 loads FIRST (into slot s%3, freed at iter s-1) so the
    // pack below waits with a partial vmcnt, never draining the queue
    if (s + 3 <= 31) {
      const int t = (s + 3) % 3;
      const int* p = g0 + (size_t)(s + 3) * 16 * MM;
      sa[t] = __builtin_nontemporal_load((const intx4*)p);
      sb[t] = __builtin_nontemporal_load((const intx4*)(p + MM));
      sc[t] = __builtin_nontemporal_load((const intx4*)(p + 32));
      sd[t] = __builtin_nontemporal_load((const intx4*)(p + MM + 32));
    }
    short8 nbf0 = bf0, nbf1 = bf1;
    if (s < 31) {  // pack step s+1 (slot (s+1)%3) -> other LDS buffer (wave-local)
      const int t = (s + 1) % 3;
#pragma unroll
      for (int i = 0; i < 4; ++i) {
        buf[(s + 1) & 1][wb0 + 10 * i] = (unsigned int)(sa[t][i] | (sb[t][i] << 16)) * 0x3F80u;
        buf[(s + 1) & 1][wb1 + 10 * i] = (unsigned int)(sc[t][i] | (sd[t][i] << 16)) * 0x3F80u;
      }
      nbf0 = bm[((s + 1) * 2 + 0) * 64 + l];
      nbf1 = bm[((s + 1) * 2 + 1) * 64 + l];
    }
    a00 = __builtin_amdgcn_mfma_f32_32x32x16_bf16(af0, bf0, a00, 0, 0, 0);
    a01 = __builtin_amdgcn_mfma_f32_32x32x16_bf16(af0, bf1, a01, 0, 0, 0);
    a10 = __builtin_amdgcn_mfma_f32_32x32x16_bf16(af1, bf0, a10, 0, 0, 0);
    a11 = __builtin_amdgcn_mfma_f32_32x32x16_bf16(af1, bf1, a11, 0, 0, 0);
    bf0 = nbf0; bf1 = nbf1;
  }

  // epilogue: squash F, weight by Y, reduce over this wave's 64 m's
  const float inv_norm = meta[64];
  const float kk = kp[0], jj = jp[0];
  const float c1 = 1.0f - kk, c2 = 1.0f + jj;
  const float s1b0 = meta[col];
  const float s1b1 = meta[32 + col];
  float p0 = 0.f, p1 = 0.f;
#pragma unroll
  for (int q = 0; q < 16; ++q) {
    const int ml = (q & 3) + 8 * (q >> 2) + 4 * half;  // verified 32x32 C/D row map
    const float ym0 = Y[m0 + ml];
    const float ym1 = Y[m0 + 32 + ml];
    {
      const float x = 1.0f - (s1b0 + a00[q]) * inv_norm;
      const float inner = x * c1 / (kk * (1.0f - 2.0f * fabsf(x)) + 1.0f);
      const float t2 = 2.0f * inner - 1.0f;
      const float fq = 0.5f + 0.5f * t2 * c2 / (-jj * (1.0f - 2.0f * fabsf(t2)) + 1.0f);
      p0 += fq * ym0;
    }
    {
      const float x = 1.0f - (s1b1 + a01[q]) * inv_norm;
      const float inner = x * c1 / (kk * (1.0f - 2.0f * fabsf(x)) + 1.0f);
      const float t2 = 2.0f * inner - 1.0f;
      const float fq = 0.5f + 0.5f * t2 * c2 / (-jj * (1.0f - 2.0f * fabsf(t2)) + 1.0f);
      p1 += fq * ym0;
    }
    {
      const float x = 1.0f - (s1b0 + a10[q]) * inv_norm;
      const float inner = x * c1 / (kk * (1.0f - 2.0f * fabsf(x)) + 1.0f);
      const float t2 = 2.0f * inner - 1.0f;
      const float fq = 0.5f + 0.5f * t2 * c2 / (-jj * (1.0f - 2.0f * fabsf(t2)) + 1.0f);
      p0 += fq * ym1;
    }
    {
      const float x = 1.0f - (s1b1 + a11[q]) * inv_norm;
      const float inner = x * c1 / (kk * (1.0f - 2.0f * fabsf(x)) + 1.0f);
      const float t2 = 2.0f * inner - 1.0f;
      const float fq = 0.5f + 0.5f * t2 * c2 / (-jj * (1.0f - 2.0f * fabsf(t2)) + 1.0f);
      p1 += fq * ym1;
    }
  }
  p0 += __shfl_xor(p0, 32);  // combine the two lane-halves
  p1 += __shfl_xor(p1, 32);
  const int gw = blockIdx.x * 8 + wv;
  if (l < 32) {
    partials[(size_t)col * NWAVES + gw] = p0;
    partials[(size_t)(32 + col) * NWAVES + gw] = p1;
  }
}

__global__ __launch_bounds__(256) void knn_finalize(
    const float* __restrict__ partials, const float* __restrict__ alphap,
    const float* __restrict__ betap, float* __restrict__ out) {
  __shared__ float red[256];
  const int b = blockIdx.x, t = threadIdx.x;
  float s = 0.f;
#pragma unroll
  for (int i = 0; i < NWAVES / 256; ++i)
    s += partials[(size_t)b * NWAVES + i * 256 + t];
  red[t] = s;
  __syncthreads();
  if (t < 64) {
    float x = red[t] + red[t + 64] + red[t + 128] + red[t + 192];
    x += __shfl_xor(x, 32);
    x += __shfl_xor(x, 16);
    x += __shfl_xor(x, 8);
    x += __shfl_xor(x, 4);
    x += __shfl_xor(x, 2);
    x += __shfl_xor(x, 1);
    if (t == 0) out[b] = betap[0] * (x * (1.0f / (float)MM) + alphap[0]);
  }
}

extern "C" void kernel_launch(void* const* d_in, const int* in_sizes, int n_in,
                              void* d_out, int out_size, void* d_ws, size_t ws_size,
                              hipStream_t stream) {
  const int* X1 = (const int*)d_in[0];     // [512, 64] int32 bits
  const int* X2 = (const int*)d_in[1];     // [512, 131072] int32 bits
  const float* Y = (const float*)d_in[3];  // [131072]
  const float* W = (const float*)d_in[4];  // [512]
  const float* alphap = (const float*)d_in[5];
  const float* betap = (const float*)d_in[6];
  const float* kp = (const float*)d_in[7];
  const float* jp = (const float*)d_in[8];

  float* partials = (float*)((char*)d_ws + WS_PART);

  knn_setup<<<17, 256, 0, stream>>>(X1, W, d_ws);
  knn_main<<<NWG, 512, 0, stream>>>(X2, Y, kp, jp, d_ws, partials);
  knn_finalize<<<BQ, 256, 0, stream>>>(partials, alphap, betap, (float*)d_out);
}